// Round 5
// baseline (2138.256 us; speedup 1.0000x reference)
//
#include <hip/hip_runtime.h>
#include <hip/hip_bf16.h>

#define N_USERS 6144
#define N_ITEMS 12288
#define N_NODES 18432
#define D 64
#define NNZ 589824
#define K_TOP 31     // K+1
#define SEG 8        // column segments
#define SEG_COLS (N_ITEMS / SEG)       // 1536
#define CAP 64       // per-row per-seg candidate buffer
#define KEEP 48      // per-seg top kept (>= K_TOP with margin)
#define SELCAP 128   // finalize selected cap

using frag_ab = __attribute__((ext_vector_type(8))) short;  // 8 bf16
using frag_cd = __attribute__((ext_vector_type(4))) float;  // 4 fp32

__device__ inline unsigned f32_to_bf16_bits(float f) {
    unsigned b = __float_as_uint(f);
    return (b + 0x7FFFu + ((b >> 16) & 1u)) >> 16;          // RNE
}
__device__ inline unsigned bf16_key(float f) {
    unsigned k = f32_to_bf16_bits(f) & 0xFFFFu;
    return k ^ ((k & 0x8000u) ? 0xFFFFu : 0x8000u);         // order-preserving u16
}

// ---------------------------------------------------------------------------
// concat user_emb + item_emb -> e0 (fp64)
__global__ void concat64_kernel(const float* __restrict__ u,
                                const float* __restrict__ it,
                                double* __restrict__ e0) {
    int i = blockIdx.x * 256 + threadIdx.x;
    const int NU = N_USERS * D;
    e0[i] = (i < NU) ? (double)u[i] : (double)it[i - NU];
}

// ---------------------------------------------------------------------------
// CSR build: count, scan, scatter (packed int2 {col, val_bits})
__global__ void count_kernel(const int* __restrict__ er, int* __restrict__ cnt) {
    int e = blockIdx.x * 256 + threadIdx.x;
    atomicAdd(&cnt[er[e]], 1);
}

__global__ __launch_bounds__(256) void scan_kernel(const int* __restrict__ cnt,
                                                   int* __restrict__ row_start,
                                                   int* __restrict__ cursor) {
    __shared__ int part[256];
    int t = threadIdx.x;
    const int PER = N_NODES / 256;                   // 72
    int s = 0;
    for (int i = 0; i < PER; ++i) s += cnt[t * PER + i];
    part[t] = s;
    __syncthreads();
    for (int off = 1; off < 256; off <<= 1) {
        int v = part[t];
        int w = (t >= off) ? part[t - off] : 0;
        __syncthreads();
        part[t] = v + w;
        __syncthreads();
    }
    int run = (t == 0) ? 0 : part[t - 1];
    for (int i = 0; i < PER; ++i) {
        int idx = t * PER + i;
        row_start[idx] = run;
        cursor[idx] = run;
        run += cnt[idx];
    }
    if (t == 255) row_start[N_NODES] = run;
}

__global__ void scatter_kernel(const int* __restrict__ er, const int* __restrict__ ec,
                               const float* __restrict__ ev,
                               int* __restrict__ cursor, int2* __restrict__ ep) {
    int e = blockIdx.x * 256 + threadIdx.x;
    int r = er[e];
    int pos = atomicAdd(&cursor[r], 1);
    ep[pos] = make_int2(ec[e], __float_as_int(ev[e]));
}

// ---------------------------------------------------------------------------
// CSR SpMM, fp64, no atomics: one wave per row, lane = dim, 4-way unrolled
__global__ __launch_bounds__(256) void spmm_csr_kernel(const int* __restrict__ row_start,
                                                       const int2* __restrict__ ep,
                                                       const double* __restrict__ x,
                                                       double* __restrict__ y) {
    int t = threadIdx.x;
    int lane = t & 63, wave = t >> 6;
    int row = blockIdx.x * 4 + wave;
    if (row >= N_NODES) return;
    int beg = row_start[row], end = row_start[row + 1];
    double a0 = 0.0, a1 = 0.0, a2 = 0.0, a3 = 0.0;
    int j = beg;
    int n4 = beg + ((end - beg) & ~3);
    for (; j < n4; j += 4) {
        int2 p0 = ep[j], p1 = ep[j + 1], p2 = ep[j + 2], p3 = ep[j + 3];
        a0 += (double)__int_as_float(p0.y) * x[(size_t)p0.x * D + lane];
        a1 += (double)__int_as_float(p1.y) * x[(size_t)p1.x * D + lane];
        a2 += (double)__int_as_float(p2.y) * x[(size_t)p2.x * D + lane];
        a3 += (double)__int_as_float(p3.y) * x[(size_t)p3.x * D + lane];
    }
    for (; j < end; ++j) {
        int2 p = ep[j];
        a0 += (double)__int_as_float(p.y) * x[(size_t)p.x * D + lane];
    }
    y[(size_t)row * D + lane] = (a0 + a1) + (a2 + a3);
}

// ---------------------------------------------------------------------------
// mean + L2 normalize (fp64). Emits fp64 (exact recompute) and bf16 (MFMA).
__global__ void mean_norm64_kernel(const double* __restrict__ e0,
                                   const double* __restrict__ e1,
                                   const double* __restrict__ e2,
                                   double* __restrict__ xn64,
                                   ushort* __restrict__ xh) {
    int t = threadIdx.x;
    int wave = t >> 6, lane = t & 63;
    int r = blockIdx.x * 4 + wave;
    size_t g = (size_t)(r + N_USERS) * D + lane;
    double s = (e0[g] + e1[g] + e2[g]) / 3.0;
    double ss = s * s;
    #pragma unroll
    for (int off = 32; off; off >>= 1) ss += __shfl_xor(ss, off);
    double norm = sqrt(ss);
    double denom = fmax(norm, 1e-12);
    double v = s / denom;
    xn64[(size_t)r * D + lane] = v;
    xh[(size_t)r * D + lane] = (ushort)f32_to_bf16_bits((float)v);
}

// ---------------------------------------------------------------------------
// Fused GEMM + streaming per-row top-KEEP preselect.
// grid = (SEG, N_ITEMS/128). Block: 128 rows x SEG_COLS cols, 12 tiles of 128.
// A fragments live in registers for the whole kernel (Xh is L2-resident).
// Per row: candidate buffer (cap 64) + bf16-key threshold, overflow->prune->retry.
__global__ __launch_bounds__(256) void gemm_select_kernel(const ushort* __restrict__ Xh,
                                                          unsigned* __restrict__ candbuf,
                                                          int* __restrict__ candcnt) {
    __shared__ unsigned s_buf[128 * CAP];     // 32 KB
    __shared__ int      s_cnt[128];
    __shared__ unsigned s_thr[128];
    __shared__ int      s_of;
    int t = threadIdx.x;
    int seg = blockIdx.x, rb = blockIdx.y;
    int lane = t & 63, wave = t >> 6;
    int wrowG = (wave >> 1) * 64, wcolG = (wave & 1) * 64;
    int ml = lane & 15, quad = lane >> 4;

    if (t < 128) { s_cnt[t] = 0; s_thr[t] = 0; }

    // A fragments: rows rb*128 + wrowG + rt*16 + ml, k = s*32 + quad*8
    frag_ab afr[4][2];
    #pragma unroll
    for (int rt = 0; rt < 4; ++rt)
        #pragma unroll
        for (int s = 0; s < 2; ++s)
            afr[rt][s] = *(const frag_ab*)&Xh[(size_t)(rb * 128 + wrowG + rt * 16 + ml) * D
                                              + s * 32 + quad * 8];
    __syncthreads();

    for (int tt = 0; tt < SEG_COLS / 128; ++tt) {
        int tilebase = seg * SEG_COLS + tt * 128;
        frag_ab bfr[4][2];
        #pragma unroll
        for (int ct = 0; ct < 4; ++ct)
            #pragma unroll
            for (int s = 0; s < 2; ++s)
                bfr[ct][s] = *(const frag_ab*)&Xh[(size_t)(tilebase + wcolG + ct * 16 + ml) * D
                                                  + s * 32 + quad * 8];
        frag_cd acc[4][4] = {};
        #pragma unroll
        for (int s = 0; s < 2; ++s)
            #pragma unroll
            for (int rt = 0; rt < 4; ++rt)
                #pragma unroll
                for (int ct = 0; ct < 4; ++ct)
                    acc[rt][ct] = __builtin_amdgcn_mfma_f32_16x16x32_bf16(
                        afr[rt][s], bfr[ct][s], acc[rt][ct], 0, 0, 0);

        // streaming selection: append values with key >= thr[row]
        unsigned long long pend = ~0ull;
        for (int it = 0; it < 8; ++it) {
            if (t == 0) s_of = 0;
            __syncthreads();
            #pragma unroll
            for (int rt = 0; rt < 4; ++rt) {
                #pragma unroll
                for (int ct = 0; ct < 4; ++ct) {
                    #pragma unroll
                    for (int rg = 0; rg < 4; ++rg) {
                        int b = rt * 16 + ct * 4 + rg;
                        if ((pend >> b) & 1ull) {
                            float v = acc[rt][ct][rg];
                            unsigned key = bf16_key(v);
                            int row = wrowG + rt * 16 + quad * 4 + rg;
                            if (key >= s_thr[row]) {
                                int pos = atomicAdd(&s_cnt[row], 1);
                                if (pos < CAP) {
                                    s_buf[row * CAP + pos] =
                                        (key << 16) | (unsigned)(tilebase + wcolG + ct * 16 + ml);
                                    pend &= ~(1ull << b);
                                }
                            } else pend &= ~(1ull << b);
                        }
                    }
                }
            }
            __syncthreads();
            if (t < 128 && s_cnt[t] > CAP) {
                // prune row t: keep top-KEEP by key (incl. boundary ties)
                int rr = t;
                int n = CAP;
                unsigned lo = 0, hi = 0xFFFFu;
                while (lo < hi) {
                    unsigned mid = (lo + hi + 1) >> 1;
                    int cc = 0;
                    for (int i = 0; i < n; ++i) cc += ((s_buf[rr * CAP + i] >> 16) >= mid);
                    if (cc >= KEEP) lo = mid; else hi = mid - 1;
                }
                unsigned T = lo;
                int k = 0;
                for (int i = 0; i < n; ++i) {
                    unsigned e = s_buf[rr * CAP + i];
                    if ((e >> 16) >= T) s_buf[rr * CAP + (k++)] = e;
                }
                s_cnt[rr] = k; s_thr[rr] = T;
                s_of = 1;
            }
            __syncthreads();
            if (!s_of) break;
        }
    }

    // write out candidates
    if (t < 128) {
        int row = t;
        int c = s_cnt[row]; if (c > CAP) c = CAP;
        int g = rb * 128 + row;
        candcnt[g * SEG + seg] = c;
        for (int i = 0; i < c; ++i)
            candbuf[(size_t)g * (SEG * CAP) + seg * CAP + i] = s_buf[row * CAP + i];
    }
}

// ---------------------------------------------------------------------------
// Finalize per row: merge SEG candidate lists, key-bisect to top-48+ties,
// fp64 recompute, rank-by-count top-31, zero + scatter output.
__global__ __launch_bounds__(256) void finalize_kernel(const unsigned* __restrict__ candbuf,
                                                       const int* __restrict__ candcnt,
                                                       const double* __restrict__ xn64,
                                                       float* __restrict__ out) {
    __shared__ unsigned L[SEG * CAP];        // <=512 entries
    __shared__ int s_base[SEG + 1];
    __shared__ int s_red[4];
    __shared__ unsigned s_selent[SELCAP];
    __shared__ double   s_selv[SELCAP];
    __shared__ double   s_xr[D];
    __shared__ int s_selcnt;
    int t = threadIdx.x;
    int r = blockIdx.x;

    if (t == 0) {
        int acc = 0;
        #pragma unroll
        for (int s = 0; s < SEG; ++s) { s_base[s] = acc; acc += candcnt[r * SEG + s]; }
        s_base[SEG] = acc;
    }
    if (t < D) s_xr[t] = xn64[(size_t)r * D + t];
    __syncthreads();
    int M = s_base[SEG];

    for (int ti = t; ti < SEG * CAP; ti += 256) {
        int seg = ti >> 6, i = ti & (CAP - 1);
        int c = s_base[seg + 1] - s_base[seg];
        if (i < c) L[s_base[seg] + i] = candbuf[(size_t)r * (SEG * CAP) + seg * CAP + i];
    }
    __syncthreads();

    // largest T with count(key >= T) >= KEEP  (M >= SEG*KEEP >= KEEP always)
    unsigned lo = 0, hi = 0xFFFFu;
    for (int it = 0; it < 16; ++it) {
        if (lo >= hi) { __syncthreads(); __syncthreads(); continue; }
        unsigned mid = (lo + hi + 1) >> 1;
        int cc = 0;
        for (int i = t; i < M; i += 256) cc += ((L[i] >> 16) >= mid);
        #pragma unroll
        for (int off = 32; off; off >>= 1) cc += __shfl_down(cc, off);
        if ((t & 63) == 0) s_red[t >> 6] = cc;
        __syncthreads();
        int ctot = s_red[0] + s_red[1] + s_red[2] + s_red[3];
        __syncthreads();
        if (ctot >= KEEP) lo = mid; else hi = mid - 1;
    }
    unsigned T = lo;

    if (t == 0) s_selcnt = 0;
    __syncthreads();
    for (int i = t; i < M; i += 256) {
        unsigned e = L[i];
        if ((e >> 16) >= T) {
            int p = atomicAdd(&s_selcnt, 1);
            if (p < SELCAP) s_selent[p] = e;
        }
    }
    __syncthreads();
    int c = s_selcnt; if (c > SELCAP) c = SELCAP;

    // fp64 recompute of selected candidates
    if (t < c) {
        int col = s_selent[t] & 0xFFFFu;
        const double* xc = xn64 + (size_t)col * D;
        double a = 0.0;
        #pragma unroll 8
        for (int k = 0; k < D; ++k) a += s_xr[k] * xc[k];
        s_selv[t] = a;
    }
    __syncthreads();

    // zero the output row
    float4* O4 = (float4*)(out + (size_t)r * N_ITEMS);
    float4 z = make_float4(0.f, 0.f, 0.f, 0.f);
    #pragma unroll
    for (int j = 0; j < 12; ++j) O4[t + 256 * j] = z;

    // rank-by-count: exact fp64 top-31, ties -> lower index
    int sel_col = -1; float sel_val = 0.f;
    if (t < c) {
        double v = s_selv[t];
        int myc = (int)(s_selent[t] & 0xFFFFu);
        int rank = 0;
        for (int j = 0; j < c; ++j) {
            double vj = s_selv[j];
            int cj = (int)(s_selent[j] & 0xFFFFu);
            rank += (vj > v || (vj == v && cj < myc)) ? 1 : 0;
        }
        if (rank < K_TOP) { sel_col = myc; sel_val = (v > 0.0) ? (float)v : 0.f; }
    }
    __syncthreads();
    if (sel_col >= 0) out[(size_t)r * N_ITEMS + sel_col] = sel_val;
}

// ---------------------------------------------------------------------------
extern "C" void kernel_launch(void* const* d_in, const int* in_sizes, int n_in,
                              void* d_out, int out_size, void* d_ws, size_t ws_size,
                              hipStream_t stream) {
    const float* user_emb = (const float*)d_in[0];
    const float* item_emb = (const float*)d_in[1];
    const int*   edge_row = (const int*)d_in[2];
    const int*   edge_col = (const int*)d_in[3];
    const float* edge_val = (const float*)d_in[4];
    float* C = (float*)d_out;

    double* e0d  = (double*)d_ws;                         // N_NODES*D
    double* e1d  = e0d + (size_t)N_NODES * D;
    double* e2d  = e1d + (size_t)N_NODES * D;
    double* xn64 = e2d + (size_t)N_NODES * D;             // N_ITEMS*D
    int2*   ep   = (int2*)(xn64 + (size_t)N_ITEMS * D);   // NNZ int2
    ushort* xh   = (ushort*)(ep + NNZ);                   // N_ITEMS*D bf16
    unsigned* candbuf = (unsigned*)(xh + (size_t)N_ITEMS * D); // N_ITEMS*SEG*CAP
    int*  candcnt   = (int*)(candbuf + (size_t)N_ITEMS * SEG * CAP);
    int*  cnt       = candcnt + (size_t)N_ITEMS * SEG;
    int*  row_start = cnt + N_NODES;
    int*  cursor    = row_start + N_NODES + 1;

    hipMemsetAsync(cnt, 0, N_NODES * sizeof(int), stream);

    concat64_kernel<<<N_NODES * D / 256, 256, 0, stream>>>(user_emb, item_emb, e0d);

    count_kernel<<<NNZ / 256, 256, 0, stream>>>(edge_row, cnt);
    scan_kernel<<<1, 256, 0, stream>>>(cnt, row_start, cursor);
    scatter_kernel<<<NNZ / 256, 256, 0, stream>>>(edge_row, edge_col, edge_val, cursor, ep);

    spmm_csr_kernel<<<(N_NODES + 3) / 4, 256, 0, stream>>>(row_start, ep, e0d, e1d);
    spmm_csr_kernel<<<(N_NODES + 3) / 4, 256, 0, stream>>>(row_start, ep, e1d, e2d);

    mean_norm64_kernel<<<N_ITEMS / 4, 256, 0, stream>>>(e0d, e1d, e2d, xn64, xh);

    dim3 ggrid(SEG, N_ITEMS / 128);
    gemm_select_kernel<<<ggrid, 256, 0, stream>>>(xh, candbuf, candcnt);

    finalize_kernel<<<N_ITEMS, 256, 0, stream>>>(candbuf, candcnt, xn64, C);
}

// Round 7
// 960.544 us; speedup vs baseline: 2.2261x; 2.2261x over previous
//
#include <hip/hip_runtime.h>
#include <hip/hip_bf16.h>

#define N_USERS 6144
#define N_ITEMS 12288
#define N_NODES 18432
#define D 64
#define NNZ 589824
#define K_TOP 31     // K+1
#define NCAND_MIN 48 // bf16 preselect margin over 31
#define NCAND_MAX 240
#define CMAX 256

using frag_ab = __attribute__((ext_vector_type(8))) short;  // 8 bf16
using frag_cd = __attribute__((ext_vector_type(4))) float;  // 4 fp32
using uint4_e = __attribute__((ext_vector_type(4))) unsigned;
using uint2_e = __attribute__((ext_vector_type(2))) unsigned;
using float4_e = __attribute__((ext_vector_type(4))) float;

__device__ inline unsigned f32_to_bf16_bits(float f) {
    unsigned b = __float_as_uint(f);
    return (b + 0x7FFFu + ((b >> 16) & 1u)) >> 16;          // RNE
}

// ---------------------------------------------------------------------------
// concat user_emb + item_emb -> e0 (fp64)
__global__ void concat64_kernel(const float* __restrict__ u,
                                const float* __restrict__ it,
                                double* __restrict__ e0) {
    int i = blockIdx.x * 256 + threadIdx.x;
    const int NU = N_USERS * D;
    e0[i] = (i < NU) ? (double)u[i] : (double)it[i - NU];
}

// ---------------------------------------------------------------------------
// CSR build: count, scan, scatter (packed int2 {col, val_bits})
__global__ void count_kernel(const int* __restrict__ er, int* __restrict__ cnt) {
    int e = blockIdx.x * 256 + threadIdx.x;
    atomicAdd(&cnt[er[e]], 1);
}

__global__ __launch_bounds__(256) void scan_kernel(const int* __restrict__ cnt,
                                                   int* __restrict__ row_start,
                                                   int* __restrict__ cursor) {
    __shared__ int part[256];
    int t = threadIdx.x;
    const int PER = N_NODES / 256;                   // 72
    int s = 0;
    for (int i = 0; i < PER; ++i) s += cnt[t * PER + i];
    part[t] = s;
    __syncthreads();
    for (int off = 1; off < 256; off <<= 1) {
        int v = part[t];
        int w = (t >= off) ? part[t - off] : 0;
        __syncthreads();
        part[t] = v + w;
        __syncthreads();
    }
    int run = (t == 0) ? 0 : part[t - 1];
    for (int i = 0; i < PER; ++i) {
        int idx = t * PER + i;
        row_start[idx] = run;
        cursor[idx] = run;
        run += cnt[idx];
    }
    if (t == 255) row_start[N_NODES] = run;
}

__global__ void scatter_kernel(const int* __restrict__ er, const int* __restrict__ ec,
                               const float* __restrict__ ev,
                               int* __restrict__ cursor, int2* __restrict__ ep) {
    int e = blockIdx.x * 256 + threadIdx.x;
    int r = er[e];
    int pos = atomicAdd(&cursor[r], 1);
    ep[pos] = make_int2(ec[e], __float_as_int(ev[e]));
}

// ---------------------------------------------------------------------------
// CSR SpMM, fp64, no atomics: one wave per row, lane = dim, 4-way unrolled
__global__ __launch_bounds__(256) void spmm_csr_kernel(const int* __restrict__ row_start,
                                                       const int2* __restrict__ ep,
                                                       const double* __restrict__ x,
                                                       double* __restrict__ y) {
    int t = threadIdx.x;
    int lane = t & 63, wave = t >> 6;
    int row = blockIdx.x * 4 + wave;
    if (row >= N_NODES) return;
    int beg = row_start[row], end = row_start[row + 1];
    double a0 = 0.0, a1 = 0.0, a2 = 0.0, a3 = 0.0;
    int j = beg;
    int n4 = beg + ((end - beg) & ~3);
    for (; j < n4; j += 4) {
        int2 p0 = ep[j], p1 = ep[j + 1], p2 = ep[j + 2], p3 = ep[j + 3];
        a0 += (double)__int_as_float(p0.y) * x[(size_t)p0.x * D + lane];
        a1 += (double)__int_as_float(p1.y) * x[(size_t)p1.x * D + lane];
        a2 += (double)__int_as_float(p2.y) * x[(size_t)p2.x * D + lane];
        a3 += (double)__int_as_float(p3.y) * x[(size_t)p3.x * D + lane];
    }
    for (; j < end; ++j) {
        int2 p = ep[j];
        a0 += (double)__int_as_float(p.y) * x[(size_t)p.x * D + lane];
    }
    y[(size_t)row * D + lane] = (a0 + a1) + (a2 + a3);
}

// ---------------------------------------------------------------------------
// mean + L2 normalize (fp64). Emits fp64 (exact recompute) and bf16 (MFMA).
__global__ void mean_norm64_kernel(const double* __restrict__ e0,
                                   const double* __restrict__ e1,
                                   const double* __restrict__ e2,
                                   double* __restrict__ xn64,
                                   ushort* __restrict__ xh) {
    int t = threadIdx.x;
    int wave = t >> 6, lane = t & 63;
    int r = blockIdx.x * 4 + wave;
    size_t g = (size_t)(r + N_USERS) * D + lane;
    double s = (e0[g] + e1[g] + e2[g]) / 3.0;
    double ss = s * s;
    #pragma unroll
    for (int off = 32; off; off >>= 1) ss += __shfl_xor(ss, off);
    double norm = sqrt(ss);
    double denom = fmax(norm, 1e-12);
    double v = s / denom;
    xn64[(size_t)r * D + lane] = v;
    xh[(size_t)r * D + lane] = (ushort)f32_to_bf16_bits((float)v);
}

// ---------------------------------------------------------------------------
// Cb = bf16(Xh * Xh^T).  128x128 tile / block, 4 waves, 16x16x32 MFMA.
// Epilogue: LDS transpose (stride 132 -> conflict-free acc writes) then
// coalesced nontemporal uint2 stores.
#define LDS_STRIDE 72    // staging stride (shorts); 2-way conflict only (free)
#define OST_STRIDE 132   // epilogue stride (shorts); banks 8q+ml/2 -> free
__global__ __launch_bounds__(256) void simgemm_kernel(const ushort* __restrict__ Xh,
                                                      ushort* __restrict__ Cb) {
    __shared__ __align__(16) ushort S[2 * 128 * LDS_STRIDE];   // 36 KB; Ost aliases
    ushort* Als = S;
    ushort* Bls = S + 128 * LDS_STRIDE;
    int t = threadIdx.x;
    int bi = blockIdx.y, bj = blockIdx.x;

    #pragma unroll
    for (int p = 0; p < 4; ++p) {
        int u4 = t + 256 * p;            // 0..1023
        int row = u4 >> 3;               // 8 uint4 per 64-short row
        int seg = u4 & 7;
        *(uint4_e*)&Als[row * LDS_STRIDE + seg * 8] =
            *(const uint4_e*)&Xh[(size_t)(bi * 128 + row) * D + seg * 8];
        *(uint4_e*)&Bls[row * LDS_STRIDE + seg * 8] =
            *(const uint4_e*)&Xh[(size_t)(bj * 128 + row) * D + seg * 8];
    }
    __syncthreads();

    int lane = t & 63, wave = t >> 6;
    int wrow = (wave >> 1) * 64, wcol = (wave & 1) * 64;
    int ml = lane & 15, quad = lane >> 4;

    frag_cd acc[4][4] = {};
    #pragma unroll
    for (int s = 0; s < 2; ++s) {
        frag_ab af[4], bf[4];
        int koff = s * 32 + quad * 8;
        #pragma unroll
        for (int rt = 0; rt < 4; ++rt)
            af[rt] = *(const frag_ab*)&Als[(wrow + rt * 16 + ml) * LDS_STRIDE + koff];
        #pragma unroll
        for (int ct = 0; ct < 4; ++ct)
            bf[ct] = *(const frag_ab*)&Bls[(wcol + ct * 16 + ml) * LDS_STRIDE + koff];
        #pragma unroll
        for (int rt = 0; rt < 4; ++rt)
            #pragma unroll
            for (int ct = 0; ct < 4; ++ct)
                acc[rt][ct] = __builtin_amdgcn_mfma_f32_16x16x32_bf16(
                    af[rt], bf[ct], acc[rt][ct], 0, 0, 0);
    }
    __syncthreads();                     // all LDS reads consumed

    // acc -> LDS (transposed layout for coalesced store)
    ushort* Ost = S;                     // 128*132 shorts = 33 KB <= 36 KB
    #pragma unroll
    for (int rt = 0; rt < 4; ++rt) {
        #pragma unroll
        for (int ct = 0; ct < 4; ++ct) {
            int row = wrow + rt * 16 + quad * 4;
            int col = wcol + ct * 16 + ml;
            #pragma unroll
            for (int r = 0; r < 4; ++r)
                Ost[(row + r) * OST_STRIDE + col] = (ushort)f32_to_bf16_bits(acc[rt][ct][r]);
        }
    }
    __syncthreads();

    // coalesced nontemporal stores: 4096 uint2 (8 B x 64 lanes = 512 B/inst)
    const size_t base = (size_t)(bi * 128) * N_ITEMS + bj * 128;
    #pragma unroll
    for (int p = 0; p < 16; ++p) {
        int i = t + 256 * p;
        int row = i >> 5, cp = i & 31;
        uint2_e v = *(const uint2_e*)&Ost[row * OST_STRIDE + cp * 4];
        __builtin_nontemporal_store(v, (uint2_e*)(Cb + base + (size_t)row * N_ITEMS + cp * 4));
    }
}

// ---------------------------------------------------------------------------
// Per-row top-31 from bf16 sim: 16-bit radix-bisection preselect (register-
// resident), fp64 recompute of <=CMAX candidates, rank-by-count selection.
__global__ __launch_bounds__(256) void topk_kernel(const ushort* __restrict__ Cb,
                                                   float* __restrict__ Cout,
                                                   const double* __restrict__ xn64) {
    __shared__ int s_red[4];
    __shared__ unsigned s_cnt;
    __shared__ int    candi[CMAX];
    __shared__ double candv[CMAX];
    __shared__ double s_xr[D];
    int t = threadIdx.x;
    int r = blockIdx.x;
    const uint4_e* Crow4 = (const uint4_e*)(Cb + (size_t)r * N_ITEMS);  // 1536 uint4

    // 48 bf16 per thread -> order-preserving u16 keys
    unsigned short u[48];
    #pragma unroll
    for (int j = 0; j < 6; ++j) {
        uint4_e f = __builtin_nontemporal_load(&Crow4[t + 256 * j]);
        #pragma unroll
        for (int q = 0; q < 4; ++q) {
            unsigned w = f[q];
            unsigned lo = w & 0xFFFFu, hi = w >> 16;
            u[j * 8 + 2 * q]     = (unsigned short)(lo ^ ((lo & 0x8000u) ? 0xFFFFu : 0x8000u));
            u[j * 8 + 2 * q + 1] = (unsigned short)(hi ^ ((hi & 0x8000u) ? 0xFFFFu : 0x8000u));
        }
    }
    if (t < D) s_xr[t] = xn64[(size_t)r * D + t];

    // bisection on 16-bit key space for count(u>=T) in [NCAND_MIN, NCAND_MAX]
    unsigned lo = 0u, hi = 0xFFFFu, T = 0u, bestT = 0u;
    int found = 0;
    for (int it = 0; it < 16; ++it) {
        unsigned mid = lo + ((hi - lo) >> 1);
        int c = 0;
        #pragma unroll
        for (int k = 0; k < 48; ++k) c += (u[k] >= mid) ? 1 : 0;
        #pragma unroll
        for (int off = 32; off; off >>= 1) c += __shfl_down(c, off);
        if ((t & 63) == 0) s_red[t >> 6] = c;
        __syncthreads();
        int ctot = s_red[0] + s_red[1] + s_red[2] + s_red[3];
        __syncthreads();
        if (ctot >= NCAND_MIN) {
            bestT = mid;
            if (ctot <= NCAND_MAX) { T = mid; found = 1; }
            else lo = mid + 1;
        } else {
            if (mid == 0u) { found = 1; T = bestT; }
            else hi = mid - 1;
        }
        if (found || lo > hi) break;     // uniform across threads
    }
    if (!found) T = bestT;

    if (t == 0) s_cnt = 0;
    __syncthreads();
    #pragma unroll
    for (int k = 0; k < 48; ++k) {
        if (u[k] >= (unsigned short)T) {
            unsigned pos = atomicAdd(&s_cnt, 1u);
            if (pos < CMAX) candi[pos] = 8 * (t + 256 * (k >> 3)) + (k & 7);
        }
    }
    __syncthreads();
    int c = (int)s_cnt; if (c > CMAX) c = CMAX;

    // fp64 recompute of candidate dots
    if (t < c) {
        const double* xc = xn64 + (size_t)candi[t] * D;
        double acc = 0.0;
        #pragma unroll 8
        for (int k = 0; k < D; ++k) acc += s_xr[k] * xc[k];
        candv[t] = acc;
    }
    __syncthreads();

    // rank-by-count: exact fp64 top-31, ties -> lower index
    int   sel_idx = -1;
    float sel_val = 0.f;
    if (t < c) {
        double v = candv[t];
        int    id = candi[t];
        int rank = 0;
        for (int j = 0; j < c; ++j) {
            double vj = candv[j];
            rank += (vj > v || (vj == v && candi[j] < id)) ? 1 : 0;
        }
        if (rank < K_TOP) {
            sel_idx = id;
            sel_val = (v > 0.0) ? (float)v : 0.f;
        }
    }

    // write zeros (nontemporal), then scatter selected (barrier orders WAW)
    float4_e* Orow4 = (float4_e*)(Cout + (size_t)r * N_ITEMS);
    float4_e z = {0.f, 0.f, 0.f, 0.f};
    #pragma unroll
    for (int j = 0; j < 12; ++j)
        __builtin_nontemporal_store(z, &Orow4[t + 256 * j]);
    __syncthreads();
    if (sel_idx >= 0) Cout[(size_t)r * N_ITEMS + sel_idx] = sel_val;
}

// ---------------------------------------------------------------------------
extern "C" void kernel_launch(void* const* d_in, const int* in_sizes, int n_in,
                              void* d_out, int out_size, void* d_ws, size_t ws_size,
                              hipStream_t stream) {
    const float* user_emb = (const float*)d_in[0];
    const float* item_emb = (const float*)d_in[1];
    const int*   edge_row = (const int*)d_in[2];
    const int*   edge_col = (const int*)d_in[3];
    const float* edge_val = (const float*)d_in[4];
    float* C = (float*)d_out;

    double* e0d  = (double*)d_ws;                         // N_NODES*D
    double* e1d  = e0d + (size_t)N_NODES * D;
    double* e2d  = e1d + (size_t)N_NODES * D;
    double* xn64 = e2d + (size_t)N_NODES * D;             // N_ITEMS*D
    int2*   ep   = (int2*)(xn64 + (size_t)N_ITEMS * D);   // NNZ int2
    ushort* xh   = (ushort*)(ep + NNZ);                   // N_ITEMS*D bf16
    ushort* Cb   = xh + (size_t)N_ITEMS * D;              // N_ITEMS^2 bf16 (302 MB)
    int*  cnt       = (int*)(Cb + (size_t)N_ITEMS * N_ITEMS);
    int*  row_start = cnt + N_NODES;
    int*  cursor    = row_start + N_NODES + 1;

    (void)hipMemsetAsync(cnt, 0, N_NODES * sizeof(int), stream);

    concat64_kernel<<<N_NODES * D / 256, 256, 0, stream>>>(user_emb, item_emb, e0d);

    count_kernel<<<NNZ / 256, 256, 0, stream>>>(edge_row, cnt);
    scan_kernel<<<1, 256, 0, stream>>>(cnt, row_start, cursor);
    scatter_kernel<<<NNZ / 256, 256, 0, stream>>>(edge_row, edge_col, edge_val, cursor, ep);

    spmm_csr_kernel<<<(N_NODES + 3) / 4, 256, 0, stream>>>(row_start, ep, e0d, e1d);
    spmm_csr_kernel<<<(N_NODES + 3) / 4, 256, 0, stream>>>(row_start, ep, e1d, e2d);

    mean_norm64_kernel<<<N_ITEMS / 4, 256, 0, stream>>>(e0d, e1d, e2d, xn64, xh);

    dim3 ggrid(N_ITEMS / 128, N_ITEMS / 128);
    simgemm_kernel<<<ggrid, 256, 0, stream>>>(xh, Cb);

    topk_kernel<<<N_ITEMS, 256, 0, stream>>>(Cb, C, xn64);
}

// Round 8
// 922.787 us; speedup vs baseline: 2.3172x; 1.0409x over previous
//
#include <hip/hip_runtime.h>
#include <hip/hip_bf16.h>

#define N_USERS 6144
#define N_ITEMS 12288
#define N_NODES 18432
#define D 64
#define NNZ 589824
#define K_TOP 31     // K+1
#define NCAND_MIN 96 // u8 preselect margin over 31 (see safety arithmetic)
#define CMAX 256

using frag_ab = __attribute__((ext_vector_type(8))) short;  // 8 bf16
using frag_cd = __attribute__((ext_vector_type(4))) float;  // 4 fp32
using uint4_e = __attribute__((ext_vector_type(4))) unsigned;
using uint2_e = __attribute__((ext_vector_type(2))) unsigned;
using float4_e = __attribute__((ext_vector_type(4))) float;

__device__ inline unsigned f32_to_bf16_bits(float f) {
    unsigned b = __float_as_uint(f);
    return (b + 0x7FFFu + ((b >> 16) & 1u)) >> 16;          // RNE
}
__device__ inline unsigned char sim_to_u8(float v) {
    float e = rintf(fmaf(v, 127.5f, 127.5f));               // [-1,1] -> [0,255]
    e = fminf(fmaxf(e, 0.f), 255.f);
    return (unsigned char)(int)e;
}

// ---------------------------------------------------------------------------
// concat user_emb + item_emb -> e0 (fp64)
__global__ void concat64_kernel(const float* __restrict__ u,
                                const float* __restrict__ it,
                                double* __restrict__ e0) {
    int i = blockIdx.x * 256 + threadIdx.x;
    const int NU = N_USERS * D;
    e0[i] = (i < NU) ? (double)u[i] : (double)it[i - NU];
}

// ---------------------------------------------------------------------------
// CSR build: count, 3-kernel parallel scan, scatter (packed int2 {col,val})
__global__ void count_kernel(const int* __restrict__ er, int* __restrict__ cnt) {
    int e = blockIdx.x * 256 + threadIdx.x;
    atomicAdd(&cnt[er[e]], 1);
}

// per-block (256 rows) local exclusive scan + block total
__global__ __launch_bounds__(256) void scanA_kernel(const int* __restrict__ cnt,
                                                    int* __restrict__ excl,
                                                    int* __restrict__ bsum) {
    __shared__ int sh[256];
    int t = threadIdx.x, b = blockIdx.x;
    int idx = b * 256 + t;
    int v = cnt[idx];
    sh[t] = v;
    __syncthreads();
    for (int off = 1; off < 256; off <<= 1) {
        int x = sh[t];
        int y = (t >= off) ? sh[t - off] : 0;
        __syncthreads();
        sh[t] = x + y;
        __syncthreads();
    }
    excl[idx] = sh[t] - v;
    if (t == 255) bsum[b] = sh[255];
}

// scan the 72 block sums (exclusive)
__global__ __launch_bounds__(128) void scanB_kernel(const int* __restrict__ bsum,
                                                    int* __restrict__ bpre) {
    __shared__ int sh[128];
    int t = threadIdx.x;
    const int NB = N_NODES / 256;                    // 72
    int v = (t < NB) ? bsum[t] : 0;
    sh[t] = v;
    __syncthreads();
    for (int off = 1; off < 128; off <<= 1) {
        int x = sh[t];
        int y = (t >= off) ? sh[t - off] : 0;
        __syncthreads();
        sh[t] = x + y;
        __syncthreads();
    }
    if (t < NB) bpre[t] = sh[t] - v;
}

__global__ __launch_bounds__(256) void scanC_kernel(const int* __restrict__ excl,
                                                    const int* __restrict__ bpre,
                                                    int* __restrict__ row_start,
                                                    int* __restrict__ cursor) {
    int idx = blockIdx.x * 256 + threadIdx.x;
    int v = excl[idx] + bpre[idx >> 8];
    row_start[idx] = v;
    cursor[idx] = v;
    if (idx == 0) row_start[N_NODES] = NNZ;
}

__global__ void scatter_kernel(const int* __restrict__ er, const int* __restrict__ ec,
                               const float* __restrict__ ev,
                               int* __restrict__ cursor, int2* __restrict__ ep) {
    int e = blockIdx.x * 256 + threadIdx.x;
    int r = er[e];
    int pos = atomicAdd(&cursor[r], 1);
    ep[pos] = make_int2(ec[e], __float_as_int(ev[e]));
}

// ---------------------------------------------------------------------------
// CSR SpMM, fp64, no atomics: one wave per row, lane = dim, 4-way unrolled
__global__ __launch_bounds__(256) void spmm_csr_kernel(const int* __restrict__ row_start,
                                                       const int2* __restrict__ ep,
                                                       const double* __restrict__ x,
                                                       double* __restrict__ y) {
    int t = threadIdx.x;
    int lane = t & 63, wave = t >> 6;
    int row = blockIdx.x * 4 + wave;
    if (row >= N_NODES) return;
    int beg = row_start[row], end = row_start[row + 1];
    double a0 = 0.0, a1 = 0.0, a2 = 0.0, a3 = 0.0;
    int j = beg;
    int n4 = beg + ((end - beg) & ~3);
    for (; j < n4; j += 4) {
        int2 p0 = ep[j], p1 = ep[j + 1], p2 = ep[j + 2], p3 = ep[j + 3];
        a0 += (double)__int_as_float(p0.y) * x[(size_t)p0.x * D + lane];
        a1 += (double)__int_as_float(p1.y) * x[(size_t)p1.x * D + lane];
        a2 += (double)__int_as_float(p2.y) * x[(size_t)p2.x * D + lane];
        a3 += (double)__int_as_float(p3.y) * x[(size_t)p3.x * D + lane];
    }
    for (; j < end; ++j) {
        int2 p = ep[j];
        a0 += (double)__int_as_float(p.y) * x[(size_t)p.x * D + lane];
    }
    y[(size_t)row * D + lane] = (a0 + a1) + (a2 + a3);
}

// ---------------------------------------------------------------------------
// mean + L2 normalize (fp64). Emits fp64 (exact recompute) and bf16 (MFMA).
__global__ void mean_norm64_kernel(const double* __restrict__ e0,
                                   const double* __restrict__ e1,
                                   const double* __restrict__ e2,
                                   double* __restrict__ xn64,
                                   ushort* __restrict__ xh) {
    int t = threadIdx.x;
    int wave = t >> 6, lane = t & 63;
    int r = blockIdx.x * 4 + wave;
    size_t g = (size_t)(r + N_USERS) * D + lane;
    double s = (e0[g] + e1[g] + e2[g]) / 3.0;
    double ss = s * s;
    #pragma unroll
    for (int off = 32; off; off >>= 1) ss += __shfl_xor(ss, off);
    double norm = sqrt(ss);
    double denom = fmax(norm, 1e-12);
    double v = s / denom;
    xn64[(size_t)r * D + lane] = v;
    xh[(size_t)r * D + lane] = (ushort)f32_to_bf16_bits((float)v);
}

// ---------------------------------------------------------------------------
// Cu8 = u8(Xh * Xh^T).  128x128 tile / block, 4 waves, 16x16x32 MFMA.
// Epilogue: u8 encode -> LDS repack (stride 136 B) -> coalesced uint2 stores.
#define LDS_STRIDE 72    // staging stride (shorts); 2-way conflict only (free)
#define OST_STRIDE 136   // epilogue stride (bytes); 8-byte aligned reads
__global__ __launch_bounds__(256) void simgemm_kernel(const ushort* __restrict__ Xh,
                                                      unsigned char* __restrict__ Cu8) {
    __shared__ __align__(16) ushort S[2 * 128 * LDS_STRIDE];   // 36 KB; Ost aliases
    ushort* Als = S;
    ushort* Bls = S + 128 * LDS_STRIDE;
    int t = threadIdx.x;
    int bi = blockIdx.y, bj = blockIdx.x;

    #pragma unroll
    for (int p = 0; p < 4; ++p) {
        int u4 = t + 256 * p;            // 0..1023
        int row = u4 >> 3;               // 8 uint4 per 64-short row
        int seg = u4 & 7;
        *(uint4_e*)&Als[row * LDS_STRIDE + seg * 8] =
            *(const uint4_e*)&Xh[(size_t)(bi * 128 + row) * D + seg * 8];
        *(uint4_e*)&Bls[row * LDS_STRIDE + seg * 8] =
            *(const uint4_e*)&Xh[(size_t)(bj * 128 + row) * D + seg * 8];
    }
    __syncthreads();

    int lane = t & 63, wave = t >> 6;
    int wrow = (wave >> 1) * 64, wcol = (wave & 1) * 64;
    int ml = lane & 15, quad = lane >> 4;

    frag_cd acc[4][4] = {};
    #pragma unroll
    for (int s = 0; s < 2; ++s) {
        frag_ab af[4], bf[4];
        int koff = s * 32 + quad * 8;
        #pragma unroll
        for (int rt = 0; rt < 4; ++rt)
            af[rt] = *(const frag_ab*)&Als[(wrow + rt * 16 + ml) * LDS_STRIDE + koff];
        #pragma unroll
        for (int ct = 0; ct < 4; ++ct)
            bf[ct] = *(const frag_ab*)&Bls[(wcol + ct * 16 + ml) * LDS_STRIDE + koff];
        #pragma unroll
        for (int rt = 0; rt < 4; ++rt)
            #pragma unroll
            for (int ct = 0; ct < 4; ++ct)
                acc[rt][ct] = __builtin_amdgcn_mfma_f32_16x16x32_bf16(
                    af[rt], bf[ct], acc[rt][ct], 0, 0, 0);
    }
    __syncthreads();                     // all LDS reads consumed

    // acc -> u8 -> LDS (row-major u8 tile, stride 136)
    unsigned char* Ost = (unsigned char*)S;          // 128*136 = 17.4 KB
    #pragma unroll
    for (int rt = 0; rt < 4; ++rt) {
        #pragma unroll
        for (int ct = 0; ct < 4; ++ct) {
            int row = wrow + rt * 16 + quad * 4;
            int col = wcol + ct * 16 + ml;
            #pragma unroll
            for (int r = 0; r < 4; ++r)
                Ost[(row + r) * OST_STRIDE + col] = sim_to_u8(acc[rt][ct][r]);
        }
    }
    __syncthreads();

    // coalesced nontemporal stores: 2048 uint2 (8 B x lanes)
    const size_t base = (size_t)(bi * 128) * N_ITEMS + bj * 128;
    #pragma unroll
    for (int p = 0; p < 8; ++p) {
        int i = t + 256 * p;             // 0..2047
        int row = i >> 4, seg = i & 15;
        uint2_e v = *(const uint2_e*)&Ost[row * OST_STRIDE + seg * 8];
        __builtin_nontemporal_store(v, (uint2_e*)(Cu8 + base + (size_t)row * N_ITEMS + seg * 8));
    }
}

// ---------------------------------------------------------------------------
// Per-row top-31 from u8 sim: 8-round bisection preselect (register-resident),
// fp64 recompute of <=CMAX candidates, rank-by-count selection.
__global__ __launch_bounds__(256) void topk_kernel(const unsigned char* __restrict__ Cu8,
                                                   float* __restrict__ Cout,
                                                   const double* __restrict__ xn64) {
    __shared__ int s_red[4];
    __shared__ unsigned s_cnt;
    __shared__ int    candi[CMAX];
    __shared__ double candv[CMAX];
    __shared__ double s_xr[D];
    int t = threadIdx.x;
    int r = blockIdx.x;
    const uint4_e* Crow4 = (const uint4_e*)(Cu8 + (size_t)r * N_ITEMS);  // 768 uint4

    // 48 u8 keys per thread (linear code is already order-preserving)
    unsigned char u[48];
    #pragma unroll
    for (int j = 0; j < 3; ++j) {
        uint4_e f = __builtin_nontemporal_load(&Crow4[t + 256 * j]);
        #pragma unroll
        for (int q = 0; q < 4; ++q) {
            unsigned w = f[q];
            u[j * 16 + q * 4 + 0] = (unsigned char)(w & 0xFF);
            u[j * 16 + q * 4 + 1] = (unsigned char)((w >> 8) & 0xFF);
            u[j * 16 + q * 4 + 2] = (unsigned char)((w >> 16) & 0xFF);
            u[j * 16 + q * 4 + 3] = (unsigned char)(w >> 24);
        }
    }
    if (t < D) s_xr[t] = xn64[(size_t)r * D + t];

    // largest T in [0,255] with count(u >= T) >= NCAND_MIN  (8 fixed rounds)
    int lo = 0, hi = 255;
    #pragma unroll
    for (int it = 0; it < 8; ++it) {
        int mid = (lo + hi + 1) >> 1;
        int c = 0;
        #pragma unroll
        for (int k = 0; k < 48; ++k) c += ((int)u[k] >= mid) ? 1 : 0;
        #pragma unroll
        for (int off = 32; off; off >>= 1) c += __shfl_down(c, off);
        if ((t & 63) == 0) s_red[t >> 6] = c;
        __syncthreads();
        int ctot = s_red[0] + s_red[1] + s_red[2] + s_red[3];
        __syncthreads();
        if (ctot >= NCAND_MIN) lo = mid; else hi = mid - 1;
    }
    int T = lo;

    if (t == 0) s_cnt = 0;
    __syncthreads();
    #pragma unroll
    for (int k = 0; k < 48; ++k) {
        if ((int)u[k] >= T) {
            unsigned pos = atomicAdd(&s_cnt, 1u);
            if (pos < CMAX) candi[pos] = 16 * (t + 256 * (k >> 4)) + (k & 15);
        }
    }
    __syncthreads();
    int c = (int)s_cnt; if (c > CMAX) c = CMAX;

    // fp64 recompute of candidate dots
    if (t < c) {
        const double* xc = xn64 + (size_t)candi[t] * D;
        double acc = 0.0;
        #pragma unroll 8
        for (int k = 0; k < D; ++k) acc += s_xr[k] * xc[k];
        candv[t] = acc;
    }
    __syncthreads();

    // rank-by-count: exact fp64 top-31, ties -> lower index
    int   sel_idx = -1;
    float sel_val = 0.f;
    if (t < c) {
        double v = candv[t];
        int    id = candi[t];
        int rank = 0;
        for (int j = 0; j < c; ++j) {
            double vj = candv[j];
            rank += (vj > v || (vj == v && candi[j] < id)) ? 1 : 0;
        }
        if (rank < K_TOP) {
            sel_idx = id;
            sel_val = (v > 0.0) ? (float)v : 0.f;
        }
    }

    // write zeros (nontemporal), then scatter selected (barrier orders WAW)
    float4_e* Orow4 = (float4_e*)(Cout + (size_t)r * N_ITEMS);
    float4_e z = {0.f, 0.f, 0.f, 0.f};
    #pragma unroll
    for (int j = 0; j < 12; ++j)
        __builtin_nontemporal_store(z, &Orow4[t + 256 * j]);
    __syncthreads();
    if (sel_idx >= 0) Cout[(size_t)r * N_ITEMS + sel_idx] = sel_val;
}

// ---------------------------------------------------------------------------
extern "C" void kernel_launch(void* const* d_in, const int* in_sizes, int n_in,
                              void* d_out, int out_size, void* d_ws, size_t ws_size,
                              hipStream_t stream) {
    const float* user_emb = (const float*)d_in[0];
    const float* item_emb = (const float*)d_in[1];
    const int*   edge_row = (const int*)d_in[2];
    const int*   edge_col = (const int*)d_in[3];
    const float* edge_val = (const float*)d_in[4];
    float* C = (float*)d_out;

    double* e0d  = (double*)d_ws;                         // N_NODES*D
    double* e1d  = e0d + (size_t)N_NODES * D;
    double* e2d  = e1d + (size_t)N_NODES * D;
    double* xn64 = e2d + (size_t)N_NODES * D;             // N_ITEMS*D
    int2*   ep   = (int2*)(xn64 + (size_t)N_ITEMS * D);   // NNZ int2
    ushort* xh   = (ushort*)(ep + NNZ);                   // N_ITEMS*D bf16
    unsigned char* Cu8 = (unsigned char*)(xh + (size_t)N_ITEMS * D);  // N_ITEMS^2 u8 (151 MB)
    int*  cnt       = (int*)(Cu8 + (size_t)N_ITEMS * N_ITEMS);
    int*  excl      = cnt + N_NODES;
    int*  row_start = excl + N_NODES;
    int*  cursor    = row_start + N_NODES + 1;
    int*  bsum      = cursor + N_NODES;
    int*  bpre      = bsum + 128;

    (void)hipMemsetAsync(cnt, 0, N_NODES * sizeof(int), stream);

    concat64_kernel<<<N_NODES * D / 256, 256, 0, stream>>>(user_emb, item_emb, e0d);

    count_kernel<<<NNZ / 256, 256, 0, stream>>>(edge_row, cnt);
    scanA_kernel<<<N_NODES / 256, 256, 0, stream>>>(cnt, excl, bsum);
    scanB_kernel<<<1, 128, 0, stream>>>(bsum, bpre);
    scanC_kernel<<<N_NODES / 256, 256, 0, stream>>>(excl, bpre, row_start, cursor);
    scatter_kernel<<<NNZ / 256, 256, 0, stream>>>(edge_row, edge_col, edge_val, cursor, ep);

    spmm_csr_kernel<<<(N_NODES + 3) / 4, 256, 0, stream>>>(row_start, ep, e0d, e1d);
    spmm_csr_kernel<<<(N_NODES + 3) / 4, 256, 0, stream>>>(row_start, ep, e1d, e2d);

    mean_norm64_kernel<<<N_ITEMS / 4, 256, 0, stream>>>(e0d, e1d, e2d, xn64, xh);

    dim3 ggrid(N_ITEMS / 128, N_ITEMS / 128);
    simgemm_kernel<<<ggrid, 256, 0, stream>>>(xh, Cu8);

    topk_kernel<<<N_ITEMS, 256, 0, stream>>>(Cu8, C, xn64);
}

// Round 9
// 908.498 us; speedup vs baseline: 2.3536x; 1.0157x over previous
//
#include <hip/hip_runtime.h>
#include <hip/hip_bf16.h>

#define N_USERS 6144
#define N_ITEMS 12288
#define N_NODES 18432
#define D 64
#define NNZ 589824
#define K_TOP 31     // K+1
#define NCAND_MIN 96 // u8 preselect margin over 31 (see r8 safety arithmetic)
#define CMAX 256

using frag_ab = __attribute__((ext_vector_type(8))) short;  // 8 bf16
using frag_cd = __attribute__((ext_vector_type(4))) float;  // 4 fp32
using uint4_e = __attribute__((ext_vector_type(4))) unsigned;
using uint2_e = __attribute__((ext_vector_type(2))) unsigned;
using float4_e = __attribute__((ext_vector_type(4))) float;

__device__ inline unsigned f32_to_bf16_bits(float f) {
    unsigned b = __float_as_uint(f);
    return (b + 0x7FFFu + ((b >> 16) & 1u)) >> 16;          // RNE
}
__device__ inline unsigned char sim_to_u8(float v) {
    float e = rintf(fmaf(v, 127.5f, 127.5f));               // [-1,1] -> [0,255]
    e = fminf(fmaxf(e, 0.f), 255.f);
    return (unsigned char)(int)e;
}

// ---------------------------------------------------------------------------
// concat user_emb + item_emb -> e0 (fp64)
__global__ void concat64_kernel(const float* __restrict__ u,
                                const float* __restrict__ it,
                                double* __restrict__ e0) {
    int i = blockIdx.x * 256 + threadIdx.x;
    const int NU = N_USERS * D;
    e0[i] = (i < NU) ? (double)u[i] : (double)it[i - NU];
}

// ---------------------------------------------------------------------------
// CSR build: count, 3-kernel parallel scan, scatter (packed int2 {col,val})
__global__ void count_kernel(const int* __restrict__ er, int* __restrict__ cnt) {
    int e = blockIdx.x * 256 + threadIdx.x;
    atomicAdd(&cnt[er[e]], 1);
}

__global__ __launch_bounds__(256) void scanA_kernel(const int* __restrict__ cnt,
                                                    int* __restrict__ excl,
                                                    int* __restrict__ bsum) {
    __shared__ int sh[256];
    int t = threadIdx.x, b = blockIdx.x;
    int idx = b * 256 + t;
    int v = cnt[idx];
    sh[t] = v;
    __syncthreads();
    for (int off = 1; off < 256; off <<= 1) {
        int x = sh[t];
        int y = (t >= off) ? sh[t - off] : 0;
        __syncthreads();
        sh[t] = x + y;
        __syncthreads();
    }
    excl[idx] = sh[t] - v;
    if (t == 255) bsum[b] = sh[255];
}

__global__ __launch_bounds__(128) void scanB_kernel(const int* __restrict__ bsum,
                                                    int* __restrict__ bpre) {
    __shared__ int sh[128];
    int t = threadIdx.x;
    const int NB = N_NODES / 256;                    // 72
    int v = (t < NB) ? bsum[t] : 0;
    sh[t] = v;
    __syncthreads();
    for (int off = 1; off < 128; off <<= 1) {
        int x = sh[t];
        int y = (t >= off) ? sh[t - off] : 0;
        __syncthreads();
        sh[t] = x + y;
        __syncthreads();
    }
    if (t < NB) bpre[t] = sh[t] - v;
}

__global__ __launch_bounds__(256) void scanC_kernel(const int* __restrict__ excl,
                                                    const int* __restrict__ bpre,
                                                    int* __restrict__ row_start,
                                                    int* __restrict__ cursor) {
    int idx = blockIdx.x * 256 + threadIdx.x;
    int v = excl[idx] + bpre[idx >> 8];
    row_start[idx] = v;
    cursor[idx] = v;
    if (idx == 0) row_start[N_NODES] = NNZ;
}

__global__ void scatter_kernel(const int* __restrict__ er, const int* __restrict__ ec,
                               const float* __restrict__ ev,
                               int* __restrict__ cursor, int2* __restrict__ ep) {
    int e = blockIdx.x * 256 + threadIdx.x;
    int r = er[e];
    int pos = atomicAdd(&cursor[r], 1);
    ep[pos] = make_int2(ec[e], __float_as_int(ev[e]));
}

// ---------------------------------------------------------------------------
// CSR SpMM layer 1 (all rows), fp64, no atomics: wave per row, lane = dim
__global__ __launch_bounds__(256) void spmm_csr_kernel(const int* __restrict__ row_start,
                                                       const int2* __restrict__ ep,
                                                       const double* __restrict__ x,
                                                       double* __restrict__ y) {
    int t = threadIdx.x;
    int lane = t & 63, wave = t >> 6;
    int row = blockIdx.x * 4 + wave;
    if (row >= N_NODES) return;
    int beg = row_start[row], end = row_start[row + 1];
    double a0 = 0.0, a1 = 0.0, a2 = 0.0, a3 = 0.0;
    int j = beg;
    int n4 = beg + ((end - beg) & ~3);
    for (; j < n4; j += 4) {
        int2 p0 = ep[j], p1 = ep[j + 1], p2 = ep[j + 2], p3 = ep[j + 3];
        a0 += (double)__int_as_float(p0.y) * x[(size_t)p0.x * D + lane];
        a1 += (double)__int_as_float(p1.y) * x[(size_t)p1.x * D + lane];
        a2 += (double)__int_as_float(p2.y) * x[(size_t)p2.x * D + lane];
        a3 += (double)__int_as_float(p3.y) * x[(size_t)p3.x * D + lane];
    }
    for (; j < end; ++j) {
        int2 p = ep[j];
        a0 += (double)__int_as_float(p.y) * x[(size_t)p.x * D + lane];
    }
    y[(size_t)row * D + lane] = (a0 + a1) + (a2 + a3);
}

// ---------------------------------------------------------------------------
// Fused: SpMM layer 2 for ITEM rows only + mean(e0,e1,e2) + L2 normalize.
// e2 is never materialized; users' layer-2 embeddings are dead code.
__global__ __launch_bounds__(256) void spmm_norm_kernel(const int* __restrict__ row_start,
                                                        const int2* __restrict__ ep,
                                                        const double* __restrict__ e0,
                                                        const double* __restrict__ e1,
                                                        double* __restrict__ xn64,
                                                        ushort* __restrict__ xh) {
    int t = threadIdx.x;
    int lane = t & 63, wave = t >> 6;
    int ir = blockIdx.x * 4 + wave;                  // item index
    int row = ir + N_USERS;
    int beg = row_start[row], end = row_start[row + 1];
    double a0 = 0.0, a1 = 0.0, a2 = 0.0, a3 = 0.0;
    int j = beg;
    int n4 = beg + ((end - beg) & ~3);
    for (; j < n4; j += 4) {
        int2 p0 = ep[j], p1 = ep[j + 1], p2 = ep[j + 2], p3 = ep[j + 3];
        a0 += (double)__int_as_float(p0.y) * e1[(size_t)p0.x * D + lane];
        a1 += (double)__int_as_float(p1.y) * e1[(size_t)p1.x * D + lane];
        a2 += (double)__int_as_float(p2.y) * e1[(size_t)p2.x * D + lane];
        a3 += (double)__int_as_float(p3.y) * e1[(size_t)p3.x * D + lane];
    }
    for (; j < end; ++j) {
        int2 p = ep[j];
        a0 += (double)__int_as_float(p.y) * e1[(size_t)p.x * D + lane];
    }
    double e2v = (a0 + a1) + (a2 + a3);

    size_t g = (size_t)row * D + lane;
    double s = (e0[g] + e1[g] + e2v) / 3.0;
    double ss = s * s;
    #pragma unroll
    for (int off = 32; off; off >>= 1) ss += __shfl_xor(ss, off);
    double norm = sqrt(ss);
    double denom = fmax(norm, 1e-12);
    double v = s / denom;
    xn64[(size_t)ir * D + lane] = v;
    xh[(size_t)ir * D + lane] = (ushort)f32_to_bf16_bits((float)v);
}

// ---------------------------------------------------------------------------
// Cu8 = u8(Xh * Xh^T), symmetric: only bi<=bj blocks computed; off-diagonal
// blocks store both (bi,bj) and the transposed (bj,bi) via a 2nd LDS image.
#define LDS_STRIDE 72    // staging stride (shorts); 2-way bank conflict (free)
#define OST_STRIDE 136   // epilogue stride (bytes); 8 B aligned, 2-way max
__global__ __launch_bounds__(256) void simgemm_kernel(const ushort* __restrict__ Xh,
                                                      unsigned char* __restrict__ Cu8) {
    __shared__ __align__(16) ushort S[2 * 128 * LDS_STRIDE];   // 36 KB
    int bi = blockIdx.y, bj = blockIdx.x;
    if (bj < bi) return;                             // lower triangle: dead block
    ushort* Als = S;
    ushort* Bls = S + 128 * LDS_STRIDE;
    int t = threadIdx.x;

    #pragma unroll
    for (int p = 0; p < 4; ++p) {
        int u4 = t + 256 * p;            // 0..1023
        int row = u4 >> 3;               // 8 uint4 per 64-short row
        int seg = u4 & 7;
        *(uint4_e*)&Als[row * LDS_STRIDE + seg * 8] =
            *(const uint4_e*)&Xh[(size_t)(bi * 128 + row) * D + seg * 8];
        *(uint4_e*)&Bls[row * LDS_STRIDE + seg * 8] =
            *(const uint4_e*)&Xh[(size_t)(bj * 128 + row) * D + seg * 8];
    }
    __syncthreads();

    int lane = t & 63, wave = t >> 6;
    int wrow = (wave >> 1) * 64, wcol = (wave & 1) * 64;
    int ml = lane & 15, quad = lane >> 4;

    frag_cd acc[4][4] = {};
    #pragma unroll
    for (int s = 0; s < 2; ++s) {
        frag_ab af[4], bf[4];
        int koff = s * 32 + quad * 8;
        #pragma unroll
        for (int rt = 0; rt < 4; ++rt)
            af[rt] = *(const frag_ab*)&Als[(wrow + rt * 16 + ml) * LDS_STRIDE + koff];
        #pragma unroll
        for (int ct = 0; ct < 4; ++ct)
            bf[ct] = *(const frag_ab*)&Bls[(wcol + ct * 16 + ml) * LDS_STRIDE + koff];
        #pragma unroll
        for (int rt = 0; rt < 4; ++rt)
            #pragma unroll
            for (int ct = 0; ct < 4; ++ct)
                acc[rt][ct] = __builtin_amdgcn_mfma_f32_16x16x32_bf16(
                    af[rt], bf[ct], acc[rt][ct], 0, 0, 0);
    }
    __syncthreads();                     // all LDS reads consumed

    // acc -> u8 -> two LDS images: Ost[row][col], Ost2[col][row]
    unsigned char* Ost  = (unsigned char*)S;                 // 17408 B
    unsigned char* Ost2 = (unsigned char*)S + 128 * OST_STRIDE; // +17408 = 34816 <= 36864
    int offdiag = (bi != bj);
    #pragma unroll
    for (int rt = 0; rt < 4; ++rt) {
        #pragma unroll
        for (int ct = 0; ct < 4; ++ct) {
            int row = wrow + rt * 16 + quad * 4;
            int col = wcol + ct * 16 + ml;
            #pragma unroll
            for (int r = 0; r < 4; ++r) {
                unsigned char q8 = sim_to_u8(acc[rt][ct][r]);
                Ost[(row + r) * OST_STRIDE + col] = q8;
                if (offdiag) Ost2[col * OST_STRIDE + row + r] = q8;
            }
        }
    }
    __syncthreads();

    // coalesced nontemporal stores: 2048 uint2 per image
    const size_t base1 = (size_t)(bi * 128) * N_ITEMS + bj * 128;
    #pragma unroll
    for (int p = 0; p < 8; ++p) {
        int i = t + 256 * p;             // 0..2047
        int row = i >> 4, seg = i & 15;
        uint2_e v = *(const uint2_e*)&Ost[row * OST_STRIDE + seg * 8];
        __builtin_nontemporal_store(v, (uint2_e*)(Cu8 + base1 + (size_t)row * N_ITEMS + seg * 8));
    }
    if (offdiag) {
        const size_t base2 = (size_t)(bj * 128) * N_ITEMS + bi * 128;
        #pragma unroll
        for (int p = 0; p < 8; ++p) {
            int i = t + 256 * p;
            int row = i >> 4, seg = i & 15;
            uint2_e v = *(const uint2_e*)&Ost2[row * OST_STRIDE + seg * 8];
            __builtin_nontemporal_store(v, (uint2_e*)(Cu8 + base2 + (size_t)row * N_ITEMS + seg * 8));
        }
    }
}

// ---------------------------------------------------------------------------
// Per-row top-31 from u8 sim: 8-round bisection preselect (register-resident),
// fp64 recompute of <=CMAX candidates, rank-by-count selection.
__global__ __launch_bounds__(256) void topk_kernel(const unsigned char* __restrict__ Cu8,
                                                   float* __restrict__ Cout,
                                                   const double* __restrict__ xn64) {
    __shared__ int s_red[4];
    __shared__ unsigned s_cnt;
    __shared__ int    candi[CMAX];
    __shared__ double candv[CMAX];
    __shared__ double s_xr[D];
    int t = threadIdx.x;
    int r = blockIdx.x;
    const uint4_e* Crow4 = (const uint4_e*)(Cu8 + (size_t)r * N_ITEMS);  // 768 uint4

    unsigned char u[48];
    #pragma unroll
    for (int j = 0; j < 3; ++j) {
        uint4_e f = __builtin_nontemporal_load(&Crow4[t + 256 * j]);
        #pragma unroll
        for (int q = 0; q < 4; ++q) {
            unsigned w = f[q];
            u[j * 16 + q * 4 + 0] = (unsigned char)(w & 0xFF);
            u[j * 16 + q * 4 + 1] = (unsigned char)((w >> 8) & 0xFF);
            u[j * 16 + q * 4 + 2] = (unsigned char)((w >> 16) & 0xFF);
            u[j * 16 + q * 4 + 3] = (unsigned char)(w >> 24);
        }
    }
    if (t < D) s_xr[t] = xn64[(size_t)r * D + t];

    // largest T in [0,255] with count(u >= T) >= NCAND_MIN  (8 fixed rounds)
    int lo = 0, hi = 255;
    #pragma unroll
    for (int it = 0; it < 8; ++it) {
        int mid = (lo + hi + 1) >> 1;
        int c = 0;
        #pragma unroll
        for (int k = 0; k < 48; ++k) c += ((int)u[k] >= mid) ? 1 : 0;
        #pragma unroll
        for (int off = 32; off; off >>= 1) c += __shfl_down(c, off);
        if ((t & 63) == 0) s_red[t >> 6] = c;
        __syncthreads();
        int ctot = s_red[0] + s_red[1] + s_red[2] + s_red[3];
        __syncthreads();
        if (ctot >= NCAND_MIN) lo = mid; else hi = mid - 1;
    }
    int T = lo;

    if (t == 0) s_cnt = 0;
    __syncthreads();
    #pragma unroll
    for (int k = 0; k < 48; ++k) {
        if ((int)u[k] >= T) {
            unsigned pos = atomicAdd(&s_cnt, 1u);
            if (pos < CMAX) candi[pos] = 16 * (t + 256 * (k >> 4)) + (k & 15);
        }
    }
    __syncthreads();
    int c = (int)s_cnt; if (c > CMAX) c = CMAX;

    // fp64 recompute of candidate dots
    if (t < c) {
        const double* xc = xn64 + (size_t)candi[t] * D;
        double acc = 0.0;
        #pragma unroll 8
        for (int k = 0; k < D; ++k) acc += s_xr[k] * xc[k];
        candv[t] = acc;
    }
    __syncthreads();

    // rank-by-count: exact fp64 top-31, ties -> lower index
    int   sel_idx = -1;
    float sel_val = 0.f;
    if (t < c) {
        double v = candv[t];
        int    id = candi[t];
        int rank = 0;
        for (int j = 0; j < c; ++j) {
            double vj = candv[j];
            rank += (vj > v || (vj == v && candi[j] < id)) ? 1 : 0;
        }
        if (rank < K_TOP) {
            sel_idx = id;
            sel_val = (v > 0.0) ? (float)v : 0.f;
        }
    }

    // write zeros (nontemporal), then scatter selected (barrier orders WAW)
    float4_e* Orow4 = (float4_e*)(Cout + (size_t)r * N_ITEMS);
    float4_e z = {0.f, 0.f, 0.f, 0.f};
    #pragma unroll
    for (int j = 0; j < 12; ++j)
        __builtin_nontemporal_store(z, &Orow4[t + 256 * j]);
    __syncthreads();
    if (sel_idx >= 0) Cout[(size_t)r * N_ITEMS + sel_idx] = sel_val;
}

// ---------------------------------------------------------------------------
extern "C" void kernel_launch(void* const* d_in, const int* in_sizes, int n_in,
                              void* d_out, int out_size, void* d_ws, size_t ws_size,
                              hipStream_t stream) {
    const float* user_emb = (const float*)d_in[0];
    const float* item_emb = (const float*)d_in[1];
    const int*   edge_row = (const int*)d_in[2];
    const int*   edge_col = (const int*)d_in[3];
    const float* edge_val = (const float*)d_in[4];
    float* C = (float*)d_out;

    double* e0d  = (double*)d_ws;                         // N_NODES*D
    double* e1d  = e0d + (size_t)N_NODES * D;
    double* xn64 = e1d + (size_t)N_NODES * D;             // N_ITEMS*D
    int2*   ep   = (int2*)(xn64 + (size_t)N_ITEMS * D);   // NNZ int2
    ushort* xh   = (ushort*)(ep + NNZ);                   // N_ITEMS*D bf16
    unsigned char* Cu8 = (unsigned char*)(xh + (size_t)N_ITEMS * D);  // 151 MB
    int*  cnt       = (int*)(Cu8 + (size_t)N_ITEMS * N_ITEMS);
    int*  excl      = cnt + N_NODES;
    int*  row_start = excl + N_NODES;
    int*  cursor    = row_start + N_NODES + 1;
    int*  bsum      = cursor + N_NODES;
    int*  bpre      = bsum + 128;

    (void)hipMemsetAsync(cnt, 0, N_NODES * sizeof(int), stream);

    concat64_kernel<<<N_NODES * D / 256, 256, 0, stream>>>(user_emb, item_emb, e0d);

    count_kernel<<<NNZ / 256, 256, 0, stream>>>(edge_row, cnt);
    scanA_kernel<<<N_NODES / 256, 256, 0, stream>>>(cnt, excl, bsum);
    scanB_kernel<<<1, 128, 0, stream>>>(bsum, bpre);
    scanC_kernel<<<N_NODES / 256, 256, 0, stream>>>(excl, bpre, row_start, cursor);
    scatter_kernel<<<NNZ / 256, 256, 0, stream>>>(edge_row, edge_col, edge_val, cursor, ep);

    spmm_csr_kernel<<<N_NODES / 4, 256, 0, stream>>>(row_start, ep, e0d, e1d);
    spmm_norm_kernel<<<N_ITEMS / 4, 256, 0, stream>>>(row_start, ep, e0d, e1d, xn64, xh);

    dim3 ggrid(N_ITEMS / 128, N_ITEMS / 128);
    simgemm_kernel<<<ggrid, 256, 0, stream>>>(xh, Cu8);

    topk_kernel<<<N_ITEMS, 256, 0, stream>>>(Cu8, C, xn64);
}

// Round 10
// 890.772 us; speedup vs baseline: 2.4005x; 1.0199x over previous
//
#include <hip/hip_runtime.h>
#include <hip/hip_bf16.h>

#define N_USERS 6144
#define N_ITEMS 12288
#define N_NODES 18432
#define D 64
#define NNZ 589824
#define K_TOP 31     // K+1
#define NCAND_MIN 96 // u8 preselect margin over 31 (r8 safety arithmetic)
#define CMAX 256
#define NB (N_NODES / 256)   // 72 scan blocks

using frag_ab = __attribute__((ext_vector_type(8))) short;  // 8 bf16
using frag_cd = __attribute__((ext_vector_type(4))) float;  // 4 fp32
using uint4_e = __attribute__((ext_vector_type(4))) unsigned;
using uint2_e = __attribute__((ext_vector_type(2))) unsigned;
using float4_e = __attribute__((ext_vector_type(4))) float;

__device__ inline unsigned f32_to_bf16_bits(float f) {
    unsigned b = __float_as_uint(f);
    return (b + 0x7FFFu + ((b >> 16) & 1u)) >> 16;          // RNE
}
__device__ inline unsigned sim_to_u8(float v) {
    float e = rintf(fmaf(v, 127.5f, 127.5f));               // [-1,1] -> [0,255]
    e = fminf(fmaxf(e, 0.f), 255.f);
    return (unsigned)(int)e;
}

// ---------------------------------------------------------------------------
// CSR build: count, scanA (per-256 local), scanC (merged block-sum scan),
// scatter (packed int2 {col, val_bits})
__global__ void count_kernel(const int* __restrict__ er, int* __restrict__ cnt) {
    int e = blockIdx.x * 256 + threadIdx.x;
    atomicAdd(&cnt[er[e]], 1);
}

__global__ __launch_bounds__(256) void scanA_kernel(const int* __restrict__ cnt,
                                                    int* __restrict__ excl,
                                                    int* __restrict__ bsum) {
    __shared__ int sh[256];
    int t = threadIdx.x, b = blockIdx.x;
    int idx = b * 256 + t;
    int v = cnt[idx];
    sh[t] = v;
    __syncthreads();
    for (int off = 1; off < 256; off <<= 1) {
        int x = sh[t];
        int y = (t >= off) ? sh[t - off] : 0;
        __syncthreads();
        sh[t] = x + y;
        __syncthreads();
    }
    excl[idx] = sh[t] - v;
    if (t == 255) bsum[b] = sh[255];
}

__global__ __launch_bounds__(256) void scanC_kernel(const int* __restrict__ excl,
                                                    const int* __restrict__ bsum,
                                                    int* __restrict__ row_start,
                                                    int* __restrict__ cursor) {
    __shared__ int sb[NB];
    int t = threadIdx.x;
    if (t < NB) sb[t] = bsum[t];
    __syncthreads();
    if (t == 0) {
        int acc = 0;
        for (int i = 0; i < NB; ++i) { int v = sb[i]; sb[i] = acc; acc += v; }
    }
    __syncthreads();
    int idx = blockIdx.x * 256 + t;
    int v = excl[idx] + sb[idx >> 8];
    row_start[idx] = v;
    cursor[idx] = v;
    if (idx == 0) row_start[N_NODES] = NNZ;
}

__global__ void scatter_kernel(const int* __restrict__ er, const int* __restrict__ ec,
                               const float* __restrict__ ev,
                               int* __restrict__ cursor, int2* __restrict__ ep) {
    int e = blockIdx.x * 256 + threadIdx.x;
    int r = er[e];
    int pos = atomicAdd(&cursor[r], 1);
    ep[pos] = make_int2(ec[e], __float_as_int(ev[e]));
}

// ---------------------------------------------------------------------------
// CSR SpMM layer 1 (all rows), fp64 accumulate, gathers DIRECTLY from the
// fp32 inputs (bit-identical to promoting into a concat'd fp64 e0).
__global__ __launch_bounds__(256) void spmm_csr_kernel(const int* __restrict__ row_start,
                                                       const int2* __restrict__ ep,
                                                       const float* __restrict__ uemb,
                                                       const float* __restrict__ iemb,
                                                       double* __restrict__ y) {
    int t = threadIdx.x;
    int lane = t & 63, wave = t >> 6;
    int row = blockIdx.x * 4 + wave;
    int beg = row_start[row], end = row_start[row + 1];
    double a0 = 0.0, a1 = 0.0, a2 = 0.0, a3 = 0.0;
    int j = beg;
    int n4 = beg + ((end - beg) & ~3);
    const float* ishift = iemb - (size_t)N_USERS * D;      // index with global col
    for (; j < n4; j += 4) {
        int2 p0 = ep[j], p1 = ep[j + 1], p2 = ep[j + 2], p3 = ep[j + 3];
        const float* x0 = (p0.x < N_USERS) ? uemb : ishift;
        const float* x1 = (p1.x < N_USERS) ? uemb : ishift;
        const float* x2 = (p2.x < N_USERS) ? uemb : ishift;
        const float* x3 = (p3.x < N_USERS) ? uemb : ishift;
        a0 += (double)__int_as_float(p0.y) * (double)x0[(size_t)p0.x * D + lane];
        a1 += (double)__int_as_float(p1.y) * (double)x1[(size_t)p1.x * D + lane];
        a2 += (double)__int_as_float(p2.y) * (double)x2[(size_t)p2.x * D + lane];
        a3 += (double)__int_as_float(p3.y) * (double)x3[(size_t)p3.x * D + lane];
    }
    for (; j < end; ++j) {
        int2 p = ep[j];
        const float* x0 = (p.x < N_USERS) ? uemb : ishift;
        a0 += (double)__int_as_float(p.y) * (double)x0[(size_t)p.x * D + lane];
    }
    y[(size_t)row * D + lane] = (a0 + a1) + (a2 + a3);
}

// ---------------------------------------------------------------------------
// Fused: SpMM layer 2 (ITEM rows only) + mean(e0,e1,e2) + L2 normalize.
__global__ __launch_bounds__(256) void spmm_norm_kernel(const int* __restrict__ row_start,
                                                        const int2* __restrict__ ep,
                                                        const float* __restrict__ iemb,
                                                        const double* __restrict__ e1,
                                                        double* __restrict__ xn64,
                                                        ushort* __restrict__ xh) {
    int t = threadIdx.x;
    int lane = t & 63, wave = t >> 6;
    int ir = blockIdx.x * 4 + wave;                  // item index
    int row = ir + N_USERS;
    int beg = row_start[row], end = row_start[row + 1];
    double a0 = 0.0, a1 = 0.0, a2 = 0.0, a3 = 0.0;
    int j = beg;
    int n4 = beg + ((end - beg) & ~3);
    for (; j < n4; j += 4) {
        int2 p0 = ep[j], p1 = ep[j + 1], p2 = ep[j + 2], p3 = ep[j + 3];
        a0 += (double)__int_as_float(p0.y) * e1[(size_t)p0.x * D + lane];
        a1 += (double)__int_as_float(p1.y) * e1[(size_t)p1.x * D + lane];
        a2 += (double)__int_as_float(p2.y) * e1[(size_t)p2.x * D + lane];
        a3 += (double)__int_as_float(p3.y) * e1[(size_t)p3.x * D + lane];
    }
    for (; j < end; ++j) {
        int2 p = ep[j];
        a0 += (double)__int_as_float(p.y) * e1[(size_t)p.x * D + lane];
    }
    double e2v = (a0 + a1) + (a2 + a3);

    double e0v = (double)iemb[(size_t)ir * D + lane];
    double s = (e0v + e1[(size_t)row * D + lane] + e2v) / 3.0;
    double ss = s * s;
    #pragma unroll
    for (int off = 32; off; off >>= 1) ss += __shfl_xor(ss, off);
    double norm = sqrt(ss);
    double denom = fmax(norm, 1e-12);
    double v = s / denom;
    xn64[(size_t)ir * D + lane] = v;
    xh[(size_t)ir * D + lane] = (ushort)f32_to_bf16_bits((float)v);
}

// ---------------------------------------------------------------------------
// Cu8 = u8(Xh * Xh^T), symmetric: only bi<=bj computed; transposed image is
// written as PACKED u32 (4 consecutive rows per lane = 4 consecutive bytes).
#define LDS_STRIDE 72    // staging stride (shorts); 2-way bank conflict (free)
#define OST_STRIDE 136   // epilogue stride (bytes); 8 B aligned, 2-way max
__global__ __launch_bounds__(256) void simgemm_kernel(const ushort* __restrict__ Xh,
                                                      unsigned char* __restrict__ Cu8) {
    __shared__ __align__(16) ushort S[2 * 128 * LDS_STRIDE];   // 36 KB
    int bi = blockIdx.y, bj = blockIdx.x;
    if (bj < bi) return;                             // lower triangle: dead block
    ushort* Als = S;
    ushort* Bls = S + 128 * LDS_STRIDE;
    int t = threadIdx.x;

    #pragma unroll
    for (int p = 0; p < 4; ++p) {
        int u4 = t + 256 * p;            // 0..1023
        int row = u4 >> 3;               // 8 uint4 per 64-short row
        int seg = u4 & 7;
        *(uint4_e*)&Als[row * LDS_STRIDE + seg * 8] =
            *(const uint4_e*)&Xh[(size_t)(bi * 128 + row) * D + seg * 8];
        *(uint4_e*)&Bls[row * LDS_STRIDE + seg * 8] =
            *(const uint4_e*)&Xh[(size_t)(bj * 128 + row) * D + seg * 8];
    }
    __syncthreads();

    int lane = t & 63, wave = t >> 6;
    int wrow = (wave >> 1) * 64, wcol = (wave & 1) * 64;
    int ml = lane & 15, quad = lane >> 4;

    frag_cd acc[4][4] = {};
    #pragma unroll
    for (int s = 0; s < 2; ++s) {
        frag_ab af[4], bf[4];
        int koff = s * 32 + quad * 8;
        #pragma unroll
        for (int rt = 0; rt < 4; ++rt)
            af[rt] = *(const frag_ab*)&Als[(wrow + rt * 16 + ml) * LDS_STRIDE + koff];
        #pragma unroll
        for (int ct = 0; ct < 4; ++ct)
            bf[ct] = *(const frag_ab*)&Bls[(wcol + ct * 16 + ml) * LDS_STRIDE + koff];
        #pragma unroll
        for (int rt = 0; rt < 4; ++rt)
            #pragma unroll
            for (int ct = 0; ct < 4; ++ct)
                acc[rt][ct] = __builtin_amdgcn_mfma_f32_16x16x32_bf16(
                    af[rt], bf[ct], acc[rt][ct], 0, 0, 0);
    }
    __syncthreads();                     // all LDS reads consumed

    // acc -> u8 -> image1 [row][col] (b8 writes) + image2 [col][row] (packed b32)
    unsigned char* Ost  = (unsigned char*)S;                    // 17408 B
    unsigned char* Ost2 = (unsigned char*)S + 128 * OST_STRIDE; // 34816 <= 36864
    int offdiag = (bi != bj);
    #pragma unroll
    for (int rt = 0; rt < 4; ++rt) {
        #pragma unroll
        for (int ct = 0; ct < 4; ++ct) {
            int row = wrow + rt * 16 + quad * 4;     // row % 4 == 0
            int col = wcol + ct * 16 + ml;
            unsigned q0 = sim_to_u8(acc[rt][ct][0]);
            unsigned q1 = sim_to_u8(acc[rt][ct][1]);
            unsigned q2 = sim_to_u8(acc[rt][ct][2]);
            unsigned q3 = sim_to_u8(acc[rt][ct][3]);
            Ost[(row + 0) * OST_STRIDE + col] = (unsigned char)q0;
            Ost[(row + 1) * OST_STRIDE + col] = (unsigned char)q1;
            Ost[(row + 2) * OST_STRIDE + col] = (unsigned char)q2;
            Ost[(row + 3) * OST_STRIDE + col] = (unsigned char)q3;
            if (offdiag)
                *(unsigned*)&Ost2[col * OST_STRIDE + row] =
                    q0 | (q1 << 8) | (q2 << 16) | (q3 << 24);
        }
    }
    __syncthreads();

    // coalesced nontemporal stores: 2048 uint2 per image
    const size_t base1 = (size_t)(bi * 128) * N_ITEMS + bj * 128;
    #pragma unroll
    for (int p = 0; p < 8; ++p) {
        int i = t + 256 * p;             // 0..2047
        int row = i >> 4, seg = i & 15;
        uint2_e v = *(const uint2_e*)&Ost[row * OST_STRIDE + seg * 8];
        __builtin_nontemporal_store(v, (uint2_e*)(Cu8 + base1 + (size_t)row * N_ITEMS + seg * 8));
    }
    if (offdiag) {
        const size_t base2 = (size_t)(bj * 128) * N_ITEMS + bi * 128;
        #pragma unroll
        for (int p = 0; p < 8; ++p) {
            int i = t + 256 * p;
            int row = i >> 4, seg = i & 15;
            uint2_e v = *(const uint2_e*)&Ost2[row * OST_STRIDE + seg * 8];
            __builtin_nontemporal_store(v, (uint2_e*)(Cu8 + base2 + (size_t)row * N_ITEMS + seg * 8));
        }
    }
}

// ---------------------------------------------------------------------------
// Per-row top-31 from u8 sim: 8-round bisection preselect (register-resident),
// fp64 recompute of <=CMAX candidates, rank-by-count selection.
__global__ __launch_bounds__(256) void topk_kernel(const unsigned char* __restrict__ Cu8,
                                                   float* __restrict__ Cout,
                                                   const double* __restrict__ xn64) {
    __shared__ int s_red[4];
    __shared__ unsigned s_cnt;
    __shared__ int    candi[CMAX];
    __shared__ double candv[CMAX];
    __shared__ double s_xr[D];
    int t = threadIdx.x;
    int r = blockIdx.x;
    const uint4_e* Crow4 = (const uint4_e*)(Cu8 + (size_t)r * N_ITEMS);  // 768 uint4

    unsigned char u[48];
    #pragma unroll
    for (int j = 0; j < 3; ++j) {
        uint4_e f = __builtin_nontemporal_load(&Crow4[t + 256 * j]);
        #pragma unroll
        for (int q = 0; q < 4; ++q) {
            unsigned w = f[q];
            u[j * 16 + q * 4 + 0] = (unsigned char)(w & 0xFF);
            u[j * 16 + q * 4 + 1] = (unsigned char)((w >> 8) & 0xFF);
            u[j * 16 + q * 4 + 2] = (unsigned char)((w >> 16) & 0xFF);
            u[j * 16 + q * 4 + 3] = (unsigned char)(w >> 24);
        }
    }
    if (t < D) s_xr[t] = xn64[(size_t)r * D + t];

    // largest T in [0,255] with count(u >= T) >= NCAND_MIN  (8 fixed rounds)
    int lo = 0, hi = 255;
    #pragma unroll
    for (int it = 0; it < 8; ++it) {
        int mid = (lo + hi + 1) >> 1;
        int c = 0;
        #pragma unroll
        for (int k = 0; k < 48; ++k) c += ((int)u[k] >= mid) ? 1 : 0;
        #pragma unroll
        for (int off = 32; off; off >>= 1) c += __shfl_down(c, off);
        if ((t & 63) == 0) s_red[t >> 6] = c;
        __syncthreads();
        int ctot = s_red[0] + s_red[1] + s_red[2] + s_red[3];
        __syncthreads();
        if (ctot >= NCAND_MIN) lo = mid; else hi = mid - 1;
    }
    int T = lo;

    if (t == 0) s_cnt = 0;
    __syncthreads();
    #pragma unroll
    for (int k = 0; k < 48; ++k) {
        if ((int)u[k] >= T) {
            unsigned pos = atomicAdd(&s_cnt, 1u);
            if (pos < CMAX) candi[pos] = 16 * (t + 256 * (k >> 4)) + (k & 15);
        }
    }
    __syncthreads();
    int c = (int)s_cnt; if (c > CMAX) c = CMAX;

    // fp64 recompute of candidate dots
    if (t < c) {
        const double* xc = xn64 + (size_t)candi[t] * D;
        double acc = 0.0;
        #pragma unroll 8
        for (int k = 0; k < D; ++k) acc += s_xr[k] * xc[k];
        candv[t] = acc;
    }
    __syncthreads();

    // rank-by-count: exact fp64 top-31, ties -> lower index
    int   sel_idx = -1;
    float sel_val = 0.f;
    if (t < c) {
        double v = candv[t];
        int    id = candi[t];
        int rank = 0;
        for (int j = 0; j < c; ++j) {
            double vj = candv[j];
            rank += (vj > v || (vj == v && candi[j] < id)) ? 1 : 0;
        }
        if (rank < K_TOP) {
            sel_idx = id;
            sel_val = (v > 0.0) ? (float)v : 0.f;
        }
    }

    // write zeros (nontemporal), then scatter selected (barrier orders WAW)
    float4_e* Orow4 = (float4_e*)(Cout + (size_t)r * N_ITEMS);
    float4_e z = {0.f, 0.f, 0.f, 0.f};
    #pragma unroll
    for (int j = 0; j < 12; ++j)
        __builtin_nontemporal_store(z, &Orow4[t + 256 * j]);
    __syncthreads();
    if (sel_idx >= 0) Cout[(size_t)r * N_ITEMS + sel_idx] = sel_val;
}

// ---------------------------------------------------------------------------
extern "C" void kernel_launch(void* const* d_in, const int* in_sizes, int n_in,
                              void* d_out, int out_size, void* d_ws, size_t ws_size,
                              hipStream_t stream) {
    const float* user_emb = (const float*)d_in[0];
    const float* item_emb = (const float*)d_in[1];
    const int*   edge_row = (const int*)d_in[2];
    const int*   edge_col = (const int*)d_in[3];
    const float* edge_val = (const float*)d_in[4];
    float* C = (float*)d_out;

    double* e1d  = (double*)d_ws;                         // N_NODES*D
    double* xn64 = e1d + (size_t)N_NODES * D;             // N_ITEMS*D
    int2*   ep   = (int2*)(xn64 + (size_t)N_ITEMS * D);   // NNZ int2
    ushort* xh   = (ushort*)(ep + NNZ);                   // N_ITEMS*D bf16
    unsigned char* Cu8 = (unsigned char*)(xh + (size_t)N_ITEMS * D);  // 151 MB
    int*  cnt       = (int*)(Cu8 + (size_t)N_ITEMS * N_ITEMS);
    int*  excl      = cnt + N_NODES;
    int*  row_start = excl + N_NODES;
    int*  cursor    = row_start + N_NODES + 1;
    int*  bsum      = cursor + N_NODES;

    (void)hipMemsetAsync(cnt, 0, N_NODES * sizeof(int), stream);

    count_kernel<<<NNZ / 256, 256, 0, stream>>>(edge_row, cnt);
    scanA_kernel<<<N_NODES / 256, 256, 0, stream>>>(cnt, excl, bsum);
    scanC_kernel<<<N_NODES / 256, 256, 0, stream>>>(excl, bsum, row_start, cursor);
    scatter_kernel<<<NNZ / 256, 256, 0, stream>>>(edge_row, edge_col, edge_val, cursor, ep);

    spmm_csr_kernel<<<N_NODES / 4, 256, 0, stream>>>(row_start, ep, user_emb, item_emb, e1d);
    spmm_norm_kernel<<<N_ITEMS / 4, 256, 0, stream>>>(row_start, ep, item_emb, e1d, xn64, xh);

    dim3 ggrid(N_ITEMS / 128, N_ITEMS / 128);
    simgemm_kernel<<<ggrid, 256, 0, stream>>>(xh, Cu8);

    topk_kernel<<<N_ITEMS, 256, 0, stream>>>(Cu8, C, xn64);
}